// Round 1
// baseline (365.306 us; speedup 1.0000x reference)
//
#include <hip/hip_runtime.h>
#include <stdint.h>

#define M_DIM 8192
#define N_DIM 4096
#define K_DIM 4096
#define NBLK  (K_DIM / 32)

typedef __attribute__((ext_vector_type(4))) float          f32x4;
typedef __attribute__((ext_vector_type(8))) short          bf16x8;
typedef __attribute__((ext_vector_type(4))) int            i32x4;
typedef __attribute__((ext_vector_type(8))) unsigned short u16x8;

// round-to-nearest-even fp32 -> bf16 bits (finite values only)
__device__ __forceinline__ unsigned short f2bf(float f) {
  unsigned u = __builtin_bit_cast(unsigned, f);
  u += 0x7fffu + ((u >> 16) & 1u);
  return (unsigned short)(u >> 16);
}

__device__ __forceinline__ void gload_lds16(const unsigned short* g, unsigned short* l) {
  __builtin_amdgcn_global_load_lds(
      (const __attribute__((address_space(1))) void*)g,
      (__attribute__((address_space(3))) void*)l, 16, 0, 0);
}

// ---------------- dequant: wq int32 [N,K], scales [N,K/32] -> wb bf16-bits [N,K]
__global__ void MXFP4_dequant_kernel(const int* __restrict__ wq,
                                     const float* __restrict__ scales,
                                     unsigned short* __restrict__ wb) {
  int t = blockIdx.x * 256 + threadIdx.x;       // one thread per 8 elements
  long e = (long)t * 8;
  int o = t >> 9;                               // row: 4096/8 = 512 threads per row
  int k = (t & 511) << 3;                       // col within row
  float s = scales[o * NBLK + (k >> 5)] * (1.0f / 7.0f);
  i32x4 q0 = *(const i32x4*)(wq + e);
  i32x4 q1 = *(const i32x4*)(wq + e + 4);
  u16x8 r;
#pragma unroll
  for (int j = 0; j < 4; ++j) r[j]     = f2bf((float)q0[j] * s);
#pragma unroll
  for (int j = 0; j < 4; ++j) r[4 + j] = f2bf((float)q1[j] * s);
  *(u16x8*)(wb + e) = r;
}

// ---------------- x fp32 -> bf16-bits
__global__ void MXFP4_cvt_kernel(const float* __restrict__ x,
                                 unsigned short* __restrict__ xb) {
  long t = (long)blockIdx.x * 256 + threadIdx.x;
  long e = t * 8;
  f32x4 v0 = *(const f32x4*)(x + e);
  f32x4 v1 = *(const f32x4*)(x + e + 4);
  u16x8 r;
#pragma unroll
  for (int j = 0; j < 4; ++j) r[j]     = f2bf(v0[j]);
#pragma unroll
  for (int j = 0; j < 4; ++j) r[4 + j] = f2bf(v1[j]);
  *(u16x8*)(xb + e) = r;
}

// ---------------- GEMM: A [M,K] bf16, B [N,K] bf16 (B^T layout), C [M,N] f32 + bias
// m97 structure: 128x128 tile, BK=32, 4 waves (2x2), global_load_lds staging,
// 16x mfma_f32_16x16x32_bf16 per K-step, acc 4x4 fragments per wave (64x64).
__global__ __launch_bounds__(256, 2) void MXFP4_gemm_kernel(
    const unsigned short* __restrict__ A,
    const unsigned short* __restrict__ B,
    const float* __restrict__ bias,
    float* __restrict__ C) {
  __shared__ unsigned short As[128 * 32];
  __shared__ unsigned short Bs[128 * 32];

  const int tid  = threadIdx.x;
  const int lane = tid & 63;
  const int wave = tid >> 6;
  const int brow = blockIdx.y * 128;
  const int bcol = blockIdx.x * 128;
  const int wm   = (wave >> 1) * 64;   // wave sub-tile origin (2x2 waves of 64x64)
  const int wn   = (wave & 1) * 64;

  // staging: thread t covers lds element offsets t*8 and 2048 + t*8 per tile
  const int r0 = tid >> 2;             // tile row 0..63
  const int c0 = (tid & 3) * 8;        // k element 0/8/16/24
  const unsigned short* ag0 = A + (long)(brow + r0) * K_DIM + c0;
  const unsigned short* ag1 = A + (long)(brow + r0 + 64) * K_DIM + c0;
  const unsigned short* bg0 = B + (long)(bcol + r0) * K_DIM + c0;
  const unsigned short* bg1 = B + (long)(bcol + r0 + 64) * K_DIM + c0;
  unsigned short* as0 = As + tid * 8;
  unsigned short* as1 = As + 2048 + tid * 8;
  unsigned short* bs0 = Bs + tid * 8;
  unsigned short* bs1 = Bs + 2048 + tid * 8;

  f32x4 acc[4][4] = {};

  const int fr = lane & 15;            // fragment 16-dim index
  const int kc = (lane >> 4) * 8;      // fragment k offset

  for (int kt = 0; kt < K_DIM / 32; ++kt) {
    gload_lds16(ag0, as0);
    gload_lds16(ag1, as1);
    gload_lds16(bg0, bs0);
    gload_lds16(bg1, bs1);
    ag0 += 32; ag1 += 32; bg0 += 32; bg1 += 32;
    __syncthreads();                   // staging complete (vmcnt drained)

    bf16x8 af[4], bfr[4];
#pragma unroll
    for (int m = 0; m < 4; ++m)
      af[m] = *(const bf16x8*)(As + (wm + m * 16 + fr) * 32 + kc);
#pragma unroll
    for (int n = 0; n < 4; ++n)
      bfr[n] = *(const bf16x8*)(Bs + (wn + n * 16 + fr) * 32 + kc);
#pragma unroll
    for (int m = 0; m < 4; ++m)
#pragma unroll
      for (int n = 0; n < 4; ++n)
        acc[m][n] = __builtin_amdgcn_mfma_f32_16x16x32_bf16(af[m], bfr[n], acc[m][n], 0, 0, 0);
    __syncthreads();                   // all reads done before next stage
  }

  // epilogue: C/D layout col = lane&15, row = (lane>>4)*4 + reg
  const int rbase = brow + wm + (lane >> 4) * 4;
  const int cn    = lane & 15;
#pragma unroll
  for (int n = 0; n < 4; ++n) {
    int col  = bcol + wn + n * 16 + cn;
    float bv = bias[col];
#pragma unroll
    for (int m = 0; m < 4; ++m) {
      int row = rbase + m * 16;
#pragma unroll
      for (int j = 0; j < 4; ++j)
        C[(long)(row + j) * N_DIM + col] = acc[m][n][j] + bv;
    }
  }
}

extern "C" void kernel_launch(void* const* d_in, const int* in_sizes, int n_in,
                              void* d_out, int out_size, void* d_ws, size_t ws_size,
                              hipStream_t stream) {
  const float* x      = (const float*)d_in[0];
  const int*   wq     = (const int*)d_in[1];
  const float* scales = (const float*)d_in[2];
  const float* bias   = (const float*)d_in[3];
  float*       out    = (float*)d_out;

  // workspace: wb (N*K bf16 = 33.5MB) then xb (M*K bf16 = 67MB); total ~96MB
  unsigned short* wb = (unsigned short*)d_ws;
  unsigned short* xb = wb + (size_t)N_DIM * K_DIM;

  MXFP4_dequant_kernel<<<(N_DIM * (long)K_DIM / 8) / 256, 256, 0, stream>>>(wq, scales, wb);
  MXFP4_cvt_kernel<<<(M_DIM * (long)K_DIM / 8) / 256, 256, 0, stream>>>(x, xb);

  dim3 grid(N_DIM / 128, M_DIM / 128);
  MXFP4_gemm_kernel<<<grid, 256, 0, stream>>>(xb, wb, bias, out);
}

// Round 2
// 327.693 us; speedup vs baseline: 1.1148x; 1.1148x over previous
//
#include <hip/hip_runtime.h>
#include <stdint.h>

#define M_DIM 8192
#define N_DIM 4096
#define K_DIM 4096
#define NBLK  (K_DIM / 32)

typedef __attribute__((ext_vector_type(4))) float          f32x4;
typedef __attribute__((ext_vector_type(8))) short          bf16x8;
typedef __attribute__((ext_vector_type(4))) int            i32x4;
typedef __attribute__((ext_vector_type(8))) unsigned short u16x8;
typedef __attribute__((address_space(3))) unsigned short   lds_us;

// round-to-nearest-even fp32 -> bf16 bits (finite values only)
__device__ __forceinline__ unsigned short f2bf(float f) {
  unsigned u = __builtin_bit_cast(unsigned, f);
  u += 0x7fffu + ((u >> 16) & 1u);
  return (unsigned short)(u >> 16);
}

__device__ __forceinline__ void stage16(const unsigned short* g, lds_us* l) {
  __builtin_amdgcn_global_load_lds(
      (const __attribute__((address_space(1))) void*)g,
      (__attribute__((address_space(3))) void*)l, 16, 0, 0);
}

// inline-asm ds_read_b128 with immediate byte offset (escapes compiler's
// conservative vmcnt insertion against in-flight global_load_lds)
template <int OFF>
__device__ __forceinline__ bf16x8 dsr(lds_us* addr) {
  bf16x8 d;
  asm volatile("ds_read_b128 %0, %1 offset:%2" : "=v"(d) : "v"(addr), "n"(OFF));
  return d;
}

// ---------------- dequant: wq int32 [N,K], scales [N,K/32] -> wb bf16-bits [N,K]
__global__ void MXFP4_dequant_kernel(const int* __restrict__ wq,
                                     const float* __restrict__ scales,
                                     unsigned short* __restrict__ wb) {
  int t = blockIdx.x * 256 + threadIdx.x;
  long e = (long)t * 8;
  int o = t >> 9;
  int k = (t & 511) << 3;
  float s = scales[o * NBLK + (k >> 5)] * (1.0f / 7.0f);
  i32x4 q0 = *(const i32x4*)(wq + e);
  i32x4 q1 = *(const i32x4*)(wq + e + 4);
  u16x8 r;
#pragma unroll
  for (int j = 0; j < 4; ++j) r[j]     = f2bf((float)q0[j] * s);
#pragma unroll
  for (int j = 0; j < 4; ++j) r[4 + j] = f2bf((float)q1[j] * s);
  *(u16x8*)(wb + e) = r;
}

// ---------------- x fp32 -> bf16-bits
__global__ void MXFP4_cvt_kernel(const float* __restrict__ x,
                                 unsigned short* __restrict__ xb) {
  long t = (long)blockIdx.x * 256 + threadIdx.x;
  long e = t * 8;
  f32x4 v0 = *(const f32x4*)(x + e);
  f32x4 v1 = *(const f32x4*)(x + e + 4);
  u16x8 r;
#pragma unroll
  for (int j = 0; j < 4; ++j) r[j]     = f2bf(v0[j]);
#pragma unroll
  for (int j = 0; j < 4; ++j) r[4 + j] = f2bf(v1[j]);
  *(u16x8*)(xb + e) = r;
}

// ---------------- GEMM: A [M,K] bf16, B [N,K] bf16 (B^T), C [M,N] f32 + bias
// 256x256 tile, BK=64, 8 waves (2Mx4N), 8-phase schedule, counted vmcnt(4),
// fragment-ordered LDS subtiles (zero bank conflict), dbuf 128KB + 2KB dummy.
//
// LDS element map: A buf b at b*16384; B buf b at 32768+b*16384; dummy 65536.
// Subtile (16 rows x 32 K) = 1024B stored in MFMA lane order:
//   lane l <-> (row l&15, k-chunk (l>>4)*8), 16B per lane.

#define BAR() __builtin_amdgcn_s_barrier()
#define WAIT_LGKM0() do { asm volatile("s_waitcnt lgkmcnt(0)" ::: "memory"); \
                          __builtin_amdgcn_sched_barrier(0); } while (0)

#define ST_A(t_, h_, BUFA_, valid_) do { \
  if (valid_) { \
    const unsigned short* s_ = srcA + (size_t)(h_) * 128 * K_DIM + (t_) * 64; \
    lds_us* d_ = lp + (BUFA_) * 16384 + ((h_) * 8 + wv) * 1024; \
    stage16(s_, d_); stage16(s_ + 32, d_ + 512); \
  } else { stage16(srcA, lp + 65536); stage16(srcA + 32, lp + 65536 + 512); } \
} while (0)

#define ST_B(t_, h_, BUFB_, valid_) do { \
  if (valid_) { \
    const unsigned short* s_ = srcB + (size_t)(h_) * 128 * K_DIM + (t_) * 64; \
    lds_us* d_ = lp + 32768 + (BUFB_) * 16384 + ((h_) * 8 + wv) * 1024; \
    stage16(s_, d_); stage16(s_ + 32, d_ + 512); \
  } else { stage16(srcB, lp + 65536); stage16(srcB + 32, lp + 65536 + 512); } \
} while (0)

#define MF(MB_, NB_, AF_, BF_) do { \
  _Pragma("unroll") \
  for (int kk_ = 0; kk_ < 2; ++kk_) \
    _Pragma("unroll") \
    for (int mm_ = 0; mm_ < 4; ++mm_) \
      _Pragma("unroll") \
      for (int nn_ = 0; nn_ < 2; ++nn_) \
        acc[(MB_) + mm_][(NB_) + nn_] = __builtin_amdgcn_mfma_f32_16x16x32_bf16( \
            AF_[mm_][kk_], BF_[nn_][kk_], acc[(MB_) + mm_][(NB_) + nn_], 0, 0, 0); \
} while (0)

// One 4-phase group computing K-tile g from buffer BUF_ (= g&1).
// Stages: ph1/ph2 -> B halves of tile tB_=g+1 into BUF_^1 (safe: not being read);
//         ph3/ph4 -> A halves of tile tA_=g+2 into BUF_ (A-region reads end ph2).
// vmcnt(4) at ph4 end: tile g+1 fully landed, A(g+2)'s 4 loads stay in flight.
#define GROUP(BUF_, tB_, tA_, vB_, vA_) do { \
  lds_us* dsA_ = lp + (BUF_) * 16384 + wm * 8192 + lane * 8; \
  lds_us* dsB_ = lp + 32768 + (BUF_) * 16384 + wn * 4096 + lane * 8; \
  /* ---- phase 1: quadrant (m0-3, n0-1) ---- */ \
  aLo[0][0] = dsr<0>(dsA_);      aLo[0][1] = dsr<1024>(dsA_); \
  aLo[1][0] = dsr<2048>(dsA_);   aLo[1][1] = dsr<3072>(dsA_); \
  aLo[2][0] = dsr<4096>(dsA_);   aLo[2][1] = dsr<5120>(dsA_); \
  aLo[3][0] = dsr<6144>(dsA_);   aLo[3][1] = dsr<7168>(dsA_); \
  bLo[0][0] = dsr<0>(dsB_);      bLo[0][1] = dsr<1024>(dsB_); \
  bLo[1][0] = dsr<2048>(dsB_);   bLo[1][1] = dsr<3072>(dsB_); \
  ST_B(tB_, 0, (BUF_) ^ 1, vB_); \
  BAR(); WAIT_LGKM0(); \
  __builtin_amdgcn_s_setprio(1); \
  MF(0, 0, aLo, bLo); \
  __builtin_amdgcn_s_setprio(0); \
  BAR(); \
  /* ---- phase 2: quadrant (m4-7, n0-1) ---- */ \
  aHi[0][0] = dsr<8192>(dsA_);   aHi[0][1] = dsr<9216>(dsA_); \
  aHi[1][0] = dsr<10240>(dsA_);  aHi[1][1] = dsr<11264>(dsA_); \
  aHi[2][0] = dsr<12288>(dsA_);  aHi[2][1] = dsr<13312>(dsA_); \
  aHi[3][0] = dsr<14336>(dsA_);  aHi[3][1] = dsr<15360>(dsA_); \
  ST_B(tB_, 1, (BUF_) ^ 1, vB_); \
  BAR(); WAIT_LGKM0(); \
  __builtin_amdgcn_s_setprio(1); \
  MF(4, 0, aHi, bLo); \
  __builtin_amdgcn_s_setprio(0); \
  BAR(); \
  /* ---- phase 3: quadrant (m0-3, n2-3) ---- */ \
  bHi[0][0] = dsr<4096>(dsB_);   bHi[0][1] = dsr<5120>(dsB_); \
  bHi[1][0] = dsr<6144>(dsB_);   bHi[1][1] = dsr<7168>(dsB_); \
  ST_A(tA_, 0, (BUF_), vA_); \
  BAR(); WAIT_LGKM0(); \
  __builtin_amdgcn_s_setprio(1); \
  MF(0, 2, aLo, bHi); \
  __builtin_amdgcn_s_setprio(0); \
  BAR(); \
  /* ---- phase 4: quadrant (m4-7, n2-3) ---- */ \
  ST_A(tA_, 1, (BUF_), vA_); \
  asm volatile("s_waitcnt vmcnt(4)" ::: "memory"); \
  BAR(); \
  __builtin_amdgcn_s_setprio(1); \
  MF(4, 2, aHi, bHi); \
  __builtin_amdgcn_s_setprio(0); \
  BAR(); \
} while (0)

__global__ __launch_bounds__(512, 2) void MXFP4_gemm_kernel(
    const unsigned short* __restrict__ A,
    const unsigned short* __restrict__ B,
    const float* __restrict__ bias,
    float* __restrict__ C) {
  __shared__ unsigned short LDS[66560];  // 130 KB
  lds_us* lp = (lds_us*)LDS;

  const int tid  = threadIdx.x;
  const int lane = tid & 63;
  const int wv   = tid >> 6;   // wave 0..7
  const int wm   = wv >> 2;    // 0..1  (M half)
  const int wn   = wv & 3;     // 0..3  (N quarter)

  // XCD-aware bijective swizzle (512 blocks % 8 == 0), tn-major within XCD
  const int bid = blockIdx.x;
  const int sw  = (bid & 7) * 64 + (bid >> 3);
  const int tn  = sw >> 5;     // 0..15
  const int tm  = sw & 31;     // 0..31
  const int brow = tm * 256;
  const int bcol = tn * 256;

  // per-thread global staging bases (fragment-order permuted source)
  const unsigned short* srcA =
      A + (size_t)(brow + wv * 16 + (lane & 15)) * K_DIM + ((lane >> 4) * 8);
  const unsigned short* srcB =
      B + (size_t)(bcol + wv * 16 + (lane & 15)) * K_DIM + ((lane >> 4) * 8);

  f32x4 acc[8][4] = {};
  bf16x8 aLo[4][2], aHi[4][2], bLo[2][2], bHi[2][2];

  // ---- prologue: tile 0 (A lo/hi, B lo/hi) + tile 1 A halves ----
  ST_A(0, 0, 0, true); ST_A(0, 1, 0, true);
  ST_B(0, 0, 0, true); ST_B(0, 1, 0, true);
  ST_A(1, 0, 1, true); ST_A(1, 1, 1, true);
  asm volatile("s_waitcnt vmcnt(4)" ::: "memory");  // tile 0 landed; A(1) in flight
  BAR();

  // ---- main loop: 31 iters x 2 K-tiles; all stage targets in range ----
  for (int it = 0; it < 31; ++it) {
    const int g0 = 2 * it;
    GROUP(0, g0 + 1, g0 + 2, true, true);
    GROUP(1, g0 + 2, g0 + 3, true, true);
  }
  // ---- tail groups 62, 63 (dummy stages keep vmcnt accounting uniform) ----
  GROUP(0, 63, 64, true, false);
  GROUP(1, 64, 65, false, false);

  // ---- epilogue: C = acc + bias;  frag: col=lane&15, row=(lane>>4)*4+j ----
  const int rb = brow + wm * 128 + (lane >> 4) * 4;
  const int cb = bcol + wn * 64 + (lane & 15);
#pragma unroll
  for (int n = 0; n < 4; ++n) {
    const int col = cb + n * 16;
    const float bv = bias[col];
#pragma unroll
    for (int m = 0; m < 8; ++m) {
      const int row = rb + m * 16;
#pragma unroll
      for (int j = 0; j < 4; ++j)
        C[(size_t)(row + j) * N_DIM + col] = acc[m][n][j] + bv;
    }
  }
}

extern "C" void kernel_launch(void* const* d_in, const int* in_sizes, int n_in,
                              void* d_out, int out_size, void* d_ws, size_t ws_size,
                              hipStream_t stream) {
  const float* x      = (const float*)d_in[0];
  const int*   wq     = (const int*)d_in[1];
  const float* scales = (const float*)d_in[2];
  const float* bias   = (const float*)d_in[3];
  float*       out    = (float*)d_out;

  unsigned short* wb = (unsigned short*)d_ws;                    // 33.5 MB
  unsigned short* xb = wb + (size_t)N_DIM * K_DIM;               // 67 MB

  MXFP4_dequant_kernel<<<(N_DIM * (long)K_DIM / 8) / 256, 256, 0, stream>>>(wq, scales, wb);
  MXFP4_cvt_kernel<<<(M_DIM * (long)K_DIM / 8) / 256, 256, 0, stream>>>(x, xb);

  MXFP4_gemm_kernel<<<512, 512, 0, stream>>>(xb, wb, bias, out);
}